// Round 3
// baseline (2174.196 us; speedup 1.0000x reference)
//
#include <hip/hip_runtime.h>
#include <math.h>

// GraphGPS GatedGCN stack, fused single cooperative kernel. R3:
// - Weights fed through the SCALAR pipe (s_load -> SGPR FMA operand):
//   wave-uniform (matrix, j-half) per wave, lane = edge/node.
// - All activations in transposed LDS: hT/AxT..ExT [72][33], eT [72][257]
//   (row strides ==1 mod 32 banks -> conflict-free b32 access).
// - e-state lives in eT (LDS), sigmoid written in-place after stats.
// - Hierarchical grid barrier (16 leaves + root).

#define TPB 512
#define NBLK 256
#define DD 70
#define NS 33      // node-buffer row stride (floats)
#define NR 257     // edge-buffer row stride (floats)
#define NLAYERS 17
#define SPL 280
#define EPS_AGG 1e-6f
#define EPS_BN 1e-5f
#define EPS_LN 1e-5f

// statl offsets
#define SCX 0
#define SHX 70
#define SCE 140
#define SHE 210
#define SB  280
#define RAW 350
#define STATL_F 640

// LDS floats: 5 node bufs [72][33]=2376 each, eT [72][257]=18504, statl 640
#define SMEM_FLOATS (2376*5 + 18504 + STATL_F)
#define SMEM_BYTES  (SMEM_FLOATS*4 + (33+32)*4 + 768 + 16)

struct GPSParams {
  const float* __restrict__ x; const int* __restrict__ ei; const float* __restrict__ ea;
  const float* __restrict__ wn; const float* __restrict__ bnn;
  const float* __restrict__ we; const float* __restrict__ web;
  const float* __restrict__ Aw[2]; const float* __restrict__ Ab[2];
  const float* __restrict__ Bw[2]; const float* __restrict__ Bb[2];
  const float* __restrict__ Cw[2]; const float* __restrict__ Cb[2];
  const float* __restrict__ Dw[2]; const float* __restrict__ Db[2];
  const float* __restrict__ Ew[2]; const float* __restrict__ Eb[2];
  const float* __restrict__ gx[2]; const float* __restrict__ bx[2];
  const float* __restrict__ ge[2]; const float* __restrict__ gbe[2];
  const float* __restrict__ c1w; const float* __restrict__ c1b;
  const float* __restrict__ lng; const float* __restrict__ lnb;
  const float* __restrict__ c2w; const float* __restrict__ c2b;
  float* __restrict__ out; float* __restrict__ stats; unsigned* __restrict__ bar;
};

__device__ __forceinline__ void grid_sync(unsigned* b) {
  __syncthreads();
  if (threadIdx.x == 0) {
    unsigned g = __hip_atomic_load(b, __ATOMIC_RELAXED, __HIP_MEMORY_SCOPE_AGENT);
    int leaf = (int)(blockIdx.x >> 4);
    unsigned a = __hip_atomic_fetch_add(b + 32 + leaf*32, 1u, __ATOMIC_ACQ_REL, __HIP_MEMORY_SCOPE_AGENT);
    bool done = false;
    if (a == 15u) {
      unsigned r = __hip_atomic_fetch_add(b + 16, 1u, __ATOMIC_ACQ_REL, __HIP_MEMORY_SCOPE_AGENT);
      if (r == 15u) {
        #pragma unroll
        for (int i2 = 0; i2 < 16; ++i2)
          __hip_atomic_store(b + 32 + i2*32, 0u, __ATOMIC_RELAXED, __HIP_MEMORY_SCOPE_AGENT);
        __hip_atomic_store(b + 16, 0u, __ATOMIC_RELAXED, __HIP_MEMORY_SCOPE_AGENT);
        __hip_atomic_store(b, g + 1u, __ATOMIC_RELEASE, __HIP_MEMORY_SCOPE_AGENT);
        done = true;
      }
    }
    if (!done) {
      while (__hip_atomic_load(b, __ATOMIC_ACQUIRE, __HIP_MEMORY_SCOPE_AGENT) == g)
        __builtin_amdgcn_s_sleep(2);
    }
  }
  __syncthreads();
}

// TAIL: j-half==1 -> j = 36+jj, clamp weight col index for jj>=34 (j>=70).
template<bool TAIL>
__device__ __forceinline__ void node_gemm(const float* __restrict__ W, const float* __restrict__ B,
                                          float* __restrict__ outbuf, const float* __restrict__ hcol,
                                          int jb, int n) {
  float acc[36];
  #pragma unroll
  for (int jj = 0; jj < 36; ++jj) acc[jj] = 0.f;
  #pragma unroll 2
  for (int kk = 0; kk < DD; ++kk) {
    float hv = hcol[kk*NS];
    const float* wr = W + kk*DD + jb;
    #pragma unroll
    for (int jj = 0; jj < 36; ++jj) {
      int ji = (TAIL && jj >= 34) ? 33 : jj;
      acc[jj] = fmaf(hv, wr[ji], acc[jj]);
    }
  }
  #pragma unroll
  for (int jj = 0; jj < 36; ++jj) {
    int ji = (TAIL && jj >= 34) ? 33 : jj;
    outbuf[(jb + jj)*NS + n] = acc[jj] + B[jb + ji];
  }
}

template<bool TAIL>
__device__ __forceinline__ void edge_gemm(const float* __restrict__ W, const float* __restrict__ ecol,
                                          float acc[36], int jb) {
  #pragma unroll
  for (int jj = 0; jj < 36; ++jj) acc[jj] = 0.f;
  #pragma unroll 2
  for (int kk = 0; kk < DD; ++kk) {
    float ev = ecol[kk*NR];
    const float* wr = W + kk*DD + jb;
    #pragma unroll
    for (int jj = 0; jj < 36; ++jj) {
      int ji = (TAIL && jj >= 34) ? 33 : jj;
      acc[jj] = fmaf(ev, wr[ji], acc[jj]);
    }
  }
}

__global__ void __launch_bounds__(TPB, 1) gps_kernel(GPSParams p) {
  extern __shared__ float smem[];
  float* hT  = smem;                 // [72][33]
  float* AxT = smem + 2376;
  float* BxT = smem + 2376*2;
  float* DxT = smem + 2376*3;
  float* ExT = smem + 2376*4;
  float* eT  = smem + 2376*5;        // [72][257]
  float* statl = eT + 18504;         // 640
  int*   ioff  = (int*)(statl + STATL_F); // 33
  int*   icur  = ioff + 33;               // 32
  unsigned char* srcloc = (unsigned char*)(icur + 32);
  unsigned char* dstloc = srcloc + 256;
  unsigned char* eidxL  = dstloc + 256;

  const int tid  = threadIdx.x;
  const int g    = blockIdx.x;
  const int lane = tid & 63;
  const int wids = __builtin_amdgcn_readfirstlane(tid >> 6);  // wave id, scalar

  // edge-GEMM roles: wave (eb, jh), lane = edge within 64-block
  const int e_jb  = (wids >> 2) * 36;      // scalar
  const int edge  = (wids & 3) * 64 + lane;
  // node-GEMM roles: wave (mat, jh), lanes 0..31 = node
  const int n_mat = wids & 3;              // scalar
  const int n_jb  = (wids >> 2) * 36;      // scalar
  // gather roles: 576 items = 32 nodes x 18 j-quads
  const int gi0 = tid, gi1 = tid + 512;

  // ---------------- CSR build ----------------
  if (tid < 32) icur[tid] = 0;
  __syncthreads();
  if (tid < 256) {
    int s0 = p.ei[g*256 + tid]         - g*32;
    int d0 = p.ei[65536 + g*256 + tid] - g*32;
    srcloc[tid] = (unsigned char)s0;
    dstloc[tid] = (unsigned char)d0;
    atomicAdd(&icur[d0], 1);
  }
  __syncthreads();
  if (tid == 0) {
    int o = 0;
    for (int n = 0; n < 32; ++n) { ioff[n] = o; o += icur[n]; }
    ioff[32] = o;
  }
  __syncthreads();
  if (tid < 32) icur[tid] = ioff[tid];
  __syncthreads();
  if (tid < 256) {
    int d0 = dstloc[tid];
    int slot = atomicAdd(&icur[d0], 1);
    eidxL[slot] = (unsigned char)tid;
  }

  // ---------------- init hT, eT ----------------
  for (int i = tid; i < DD*32; i += TPB) {
    int j = i >> 5, n = i & 31;
    hT[j*NS + n] = fmaf(p.x[g*32 + n], p.wn[j], p.bnn[j]);
  }
  for (int i = tid; i < DD*256; i += TPB) {
    int j = i >> 8, e3 = i & 255;
    eT[j*NR + e3] = fmaf(p.ea[g*256 + e3], p.we[j], p.web[j]);
  }
  for (int i = tid; i < 2*NR; i += TPB) {       // zero pad rows 70,71
    int j = 70 + i / NR, c = i % NR;
    eT[j*NR + c] = 0.f;
  }
  __syncthreads();

  // ---------------- layer loop ----------------
  #pragma unroll 1
  for (int L = 0; L < NLAYERS; ++L) {
    const int s = (L == 0) ? 0 : 1;
    // scalar weight/bias/output selection for this thread's node wave
    const float* Wn = (n_mat == 0) ? p.Aw[s] : (n_mat == 1) ? p.Bw[s] : (n_mat == 2) ? p.Dw[s] : p.Ew[s];
    const float* Bn = (n_mat == 0) ? p.Ab[s] : (n_mat == 1) ? p.Bb[s] : (n_mat == 2) ? p.Db[s] : p.Eb[s];
    float* nbuf = (n_mat == 0) ? AxT : (n_mat == 1) ? BxT : (n_mat == 2) ? DxT : ExT;

    // A: bias-sum + node GEMMs (scalar-pipe weights)
    if (tid < DD) statl[SB + tid] = p.Cb[s][tid] + p.Db[s][tid] + p.Eb[s][tid];
    if (lane < 32) {
      if (n_jb == 0) node_gemm<false>(Wn, Bn, nbuf, hT + lane, 0,  lane);
      else           node_gemm<true >(Wn, Bn, nbuf, hT + lane, 36, lane);
    }
    __syncthreads();

    // B: edge GEMM + Dx[dst]+Ex[src]+bias; save eold
    float en[36], eold[36];
    if (e_jb == 0) edge_gemm<false>(p.Cw[s], eT + edge, en, 0);
    else           edge_gemm<true >(p.Cw[s], eT + edge, en, 36);
    {
      int dl = dstloc[edge], sl = srcloc[edge];
      #pragma unroll
      for (int jj = 0; jj < 36; ++jj) {
        if (e_jb == 0 || jj < 34) {
          int j = e_jb + jj;
          en[jj] += DxT[j*NS + dl] + ExT[j*NS + sl] + statl[SB + j];
          eold[jj] = eT[j*NR + edge];
        } else { en[jj] = 0.f; eold[jj] = 0.f; }
      }
    }
    __syncthreads();          // all eT reads done
    #pragma unroll
    for (int jj = 0; jj < 36; ++jj)
      if (e_jb == 0 || jj < 34) eT[(e_jb + jj)*NR + edge] = en[jj];
    __syncthreads();

    // D: e-stats (70 cols x 4 quarters of 64 edges)
    if (tid < SPL) {
      int col = tid % DD, q = tid / DD;
      float sm = 0.f, sq = 0.f;
      const float* base = eT + col*NR + q*64;
      for (int r = 0; r < 64; ++r) { float v = base[r]; sm += v; sq = fmaf(v, v, sq); }
      atomicAdd(&p.stats[L*SPL + 140 + col], sm);
      atomicAdd(&p.stats[L*SPL + 210 + col], sq);
    }
    __syncthreads();

    // E: sigmoid in place (rows 70,71 get 0)
    #pragma unroll
    for (int jj = 0; jj < 36; ++jj) {
      int j = e_jb + jj;
      float sv = (e_jb == 0 || jj < 34) ? (1.f / (1.f + __expf(-en[jj]))) : 0.f;
      eT[j*NR + edge] = sv;
    }
    __syncthreads();

    // F: gather: x_new = Ax + num/den  (into AxT)
    {
      auto gath = [&](int item) {
        int n = item / 18, jq = item % 18, jo = jq*4;
        float nm0=0,nm1=0,nm2=0,nm3=0, dn0=0,dn1=0,dn2=0,dn3=0;
        int pb = ioff[n], pe = ioff[n+1];
        for (int pp = pb; pp < pe; ++pp) {
          int e2 = eidxL[pp]; int sl2 = srcloc[e2];
          const float* sgp = eT + e2;
          const float* bxp = BxT + sl2;
          float s0 = sgp[(jo+0)*NR], s1 = sgp[(jo+1)*NR], s2 = sgp[(jo+2)*NR], s3 = sgp[(jo+3)*NR];
          float b0 = bxp[(jo+0)*NS], b1 = bxp[(jo+1)*NS], b2 = bxp[(jo+2)*NS], b3 = bxp[(jo+3)*NS];
          nm0 = fmaf(s0,b0,nm0); nm1 = fmaf(s1,b1,nm1); nm2 = fmaf(s2,b2,nm2); nm3 = fmaf(s3,b3,nm3);
          dn0 += s0; dn1 += s1; dn2 += s2; dn3 += s3;
        }
        float* axp = AxT + n;
        axp[(jo+0)*NS] += nm0/(dn0+EPS_AGG);
        axp[(jo+1)*NS] += nm1/(dn1+EPS_AGG);
        axp[(jo+2)*NS] += nm2/(dn2+EPS_AGG);
        axp[(jo+3)*NS] += nm3/(dn3+EPS_AGG);
      };
      gath(gi0);
      if (tid < 64) gath(gi1);
    }
    __syncthreads();

    // G: x-stats (70 cols x 2 halves of 16 nodes)
    if (tid < 140) {
      int col = tid % DD, h2 = tid / DD;
      float sm = 0.f, sq = 0.f;
      const float* base = AxT + col*NS + h2*16;
      for (int r = 0; r < 16; ++r) { float v = base[r]; sm += v; sq = fmaf(v, v, sq); }
      atomicAdd(&p.stats[L*SPL + col], sm);
      atomicAdd(&p.stats[L*SPL + 70 + col], sq);
    }

    // H: global barrier
    grid_sync(p.bar);

    // I: load raw stats, compute BN scale/shift
    if (tid < SPL)
      statl[RAW + tid] = __hip_atomic_load(&p.stats[L*SPL + tid], __ATOMIC_RELAXED, __HIP_MEMORY_SCOPE_AGENT);
    __syncthreads();
    if (tid < 70) {
      float mean = statl[RAW + tid] * (1.f/8192.f);
      float var  = statl[RAW + 70 + tid] * (1.f/8192.f) - mean*mean;
      float sc = p.gx[s][tid] * rsqrtf(var + EPS_BN);
      statl[SCX + tid] = sc;
      statl[SHX + tid] = fmaf(-mean, sc, p.bx[s][tid]);
    } else if (tid < 140) {
      int j = tid - 70;
      float mean = statl[RAW + 140 + j] * (1.f/65536.f);
      float var  = statl[RAW + 210 + j] * (1.f/65536.f) - mean*mean;
      float sc = p.ge[s][j] * rsqrtf(var + EPS_BN);
      statl[SCE + j] = sc;
      statl[SHE + j] = fmaf(-mean, sc, p.gbe[s][j]);
    }
    __syncthreads();

    // J: apply BN+ReLU+residual
    for (int i = tid; i < DD*32; i += TPB) {
      int j = i >> 5, n = i & 31;
      float xn = AxT[j*NS + n];
      hT[j*NS + n] += fmaxf(fmaf(xn, statl[SCX + j], statl[SHX + j]), 0.f);
    }
    #pragma unroll
    for (int jj = 0; jj < 36; ++jj) {
      if (e_jb == 0 || jj < 34) {
        int j = e_jb + jj;
        eT[j*NR + edge] = eold[jj] + fmaxf(fmaf(en[jj], statl[SCE + j], statl[SHE + j]), 0.f);
      }
    }
    __syncthreads();
  }

  // ---------------- readout ----------------
  if (tid < DD) {
    float mx = -3.4e38f, sm = 0.f;
    const float* hr = hT + tid*NS;
    for (int r = 0; r < 32; ++r) { float v = hr[r]; mx = fmaxf(mx, v); sm += v; }
    statl[tid]      = mx;               // gmp
    statl[70 + tid] = sm * (1.f/32.f);  // gap
  }
  __syncthreads();
  if (tid < 256) {
    float a = p.c1b[tid];
    for (int k = 0; k < 70; ++k) a = fmaf(statl[k],      p.c1w[k*256 + tid], a);
    for (int k = 0; k < 70; ++k) a = fmaf(statl[70 + k], p.c1w[(70 + k)*256 + tid], a);
    AxT[tid] = fmaxf(a, 0.f);
  }
  __syncthreads();
  if (tid == 0) {
    float sm = 0.f, sq = 0.f;
    for (int k = 0; k < 256; ++k) { float v = AxT[k]; sm += v; sq = fmaf(v, v, sq); }
    float mean = sm * (1.f/256.f);
    float var  = sq * (1.f/256.f) - mean*mean;
    statl[300] = mean;
    statl[301] = rsqrtf(var + EPS_LN);
  }
  __syncthreads();
  if (tid < 256) {
    float v = (AxT[tid] - statl[300]) * statl[301];
    BxT[tid] = fmaf(v, p.lng[tid], p.lnb[tid]);
  }
  __syncthreads();
  if (tid < 10) {
    float a = p.c2b[tid];
    for (int k = 0; k < 256; ++k) a = fmaf(BxT[k], p.c2w[k*10 + tid], a);
    p.out[g*10 + tid] = a;
  }
}

extern "C" void kernel_launch(void* const* d_in, const int* in_sizes, int n_in,
                              void* d_out, int out_size, void* d_ws, size_t ws_size,
                              hipStream_t stream) {
  (void)in_sizes; (void)n_in; (void)out_size; (void)ws_size;
  GPSParams p;
  p.x   = (const float*)d_in[0];
  p.ei  = (const int*)  d_in[1];
  p.ea  = (const float*)d_in[2];
  p.wn  = (const float*)d_in[4];  p.bnn = (const float*)d_in[5];
  p.we  = (const float*)d_in[6];  p.web = (const float*)d_in[7];
  int i = 8;
  for (int s = 0; s < 2; ++s) {
    p.Aw[s] = (const float*)d_in[i++]; p.Ab[s] = (const float*)d_in[i++];
    p.Bw[s] = (const float*)d_in[i++]; p.Bb[s] = (const float*)d_in[i++];
    p.Cw[s] = (const float*)d_in[i++]; p.Cb[s] = (const float*)d_in[i++];
    p.Dw[s] = (const float*)d_in[i++]; p.Db[s] = (const float*)d_in[i++];
    p.Ew[s] = (const float*)d_in[i++]; p.Eb[s] = (const float*)d_in[i++];
    p.gx[s] = (const float*)d_in[i++]; p.bx[s] = (const float*)d_in[i++];
    p.ge[s] = (const float*)d_in[i++]; p.gbe[s] = (const float*)d_in[i++];
  }
  p.c1w = (const float*)d_in[36]; p.c1b = (const float*)d_in[37];
  p.lng = (const float*)d_in[38]; p.lnb = (const float*)d_in[39];
  p.c2w = (const float*)d_in[40]; p.c2b = (const float*)d_in[41];
  p.out = (float*)d_out;
  p.bar = (unsigned*)d_ws;
  p.stats = (float*)((char*)d_ws + 4096);

  // zero barrier + stats (ws is not re-poisoned between replays)
  hipMemsetAsync(d_ws, 0, 4096 + NLAYERS*SPL*4, stream);

  hipFuncSetAttribute((const void*)gps_kernel,
                      hipFuncAttributeMaxDynamicSharedMemorySize, SMEM_BYTES);

  void* args[] = { (void*)&p };
  hipError_t err = hipLaunchCooperativeKernel((const void*)gps_kernel,
                                              dim3(NBLK), dim3(TPB),
                                              args, SMEM_BYTES, stream);
  if (err != hipSuccess) {
    gps_kernel<<<dim3(NBLK), dim3(TPB), SMEM_BYTES, stream>>>(p);
  }
}

// Round 4
// 1441.046 us; speedup vs baseline: 1.5088x; 1.5088x over previous
//
#include <hip/hip_runtime.h>
#include <math.h>

// GraphGPS GatedGCN stack, fused single cooperative kernel. R4:
// - Register-tiled GEMMs: edge = 4 edges x 9 cols per thread (acc[4][9]),
//   node = 1 node x 9 cols x k-half (shfl-combined). FMA:LDS ~11 for edges.
// - Weights staged TRANSPOSED in LDS (W_T[j][K], K-stride 80, zero pads)
//   so k-chunks are aligned b128 broadcasts.
// - e-state k-major eT[70][256] in LDS (contiguous 1KB row reads).
// - e-stats from registers via wave shfl_xor; sigmoid written in place.
// - 8-slot stats pre-aggregation (atomic depth 32), hierarchical grid barrier.

#define TPB 512
#define NBLK 256
#define DD 70
#define ETS 256      // eT row stride (floats)
#define NBS 80       // node-buffer row stride
#define SLS 80       // slab K-stride
#define NLAYERS 17
#define SPL 280
#define NSLOT 8
#define EPS_AGG 1e-6f
#define EPS_BN 1e-5f
#define EPS_LN 1e-5f

// statl offsets
#define SCX 0
#define SHX 72
#define SCE 144
#define SHE 216
#define SBO 288
#define BAO 360
#define BBO 432
#define ZBO 504
#define STATL_F 576

#define OFF_ET   0
#define OFF_HN   (OFF_ET + DD*ETS)            // 17920
#define OFF_AX   (OFF_HN + 32*NBS)
#define OFF_BX   (OFF_AX + 32*NBS)
#define OFF_DX   (OFF_BX + 32*NBS)
#define OFF_EX   (OFF_DX + 32*NBS)
#define OFF_SLAB (OFF_EX + 32*NBS)            // 72*80 = 5760
#define OFF_STATL (OFF_SLAB + 72*SLS)
#define SMEM_FLOATS (OFF_STATL + STATL_F)     // 37056
#define SMEM_BYTES  (SMEM_FLOATS*4 + (32+33)*4 + 768 + 16)

struct GPSParams {
  const float* __restrict__ x; const int* __restrict__ ei; const float* __restrict__ ea;
  const float* __restrict__ wn; const float* __restrict__ bnn;
  const float* __restrict__ we; const float* __restrict__ web;
  const float* __restrict__ Aw[2]; const float* __restrict__ Ab[2];
  const float* __restrict__ Bw[2]; const float* __restrict__ Bb[2];
  const float* __restrict__ Cw[2]; const float* __restrict__ Cb[2];
  const float* __restrict__ Dw[2]; const float* __restrict__ Db[2];
  const float* __restrict__ Ew[2]; const float* __restrict__ Eb[2];
  const float* __restrict__ gx[2]; const float* __restrict__ bx[2];
  const float* __restrict__ ge[2]; const float* __restrict__ gbe[2];
  const float* __restrict__ c1w; const float* __restrict__ c1b;
  const float* __restrict__ lng; const float* __restrict__ lnb;
  const float* __restrict__ c2w; const float* __restrict__ c2b;
  float* __restrict__ out; float* __restrict__ stats; unsigned* __restrict__ bar;
};

__device__ __forceinline__ void grid_sync(unsigned* b) {
  __syncthreads();
  if (threadIdx.x == 0) {
    unsigned g = __hip_atomic_load(b, __ATOMIC_RELAXED, __HIP_MEMORY_SCOPE_AGENT);
    int leaf = (int)(blockIdx.x >> 4);
    unsigned a = __hip_atomic_fetch_add(b + 32 + leaf*32, 1u, __ATOMIC_ACQ_REL, __HIP_MEMORY_SCOPE_AGENT);
    bool done = false;
    if (a == 15u) {
      unsigned r = __hip_atomic_fetch_add(b + 16, 1u, __ATOMIC_ACQ_REL, __HIP_MEMORY_SCOPE_AGENT);
      if (r == 15u) {
        #pragma unroll
        for (int i2 = 0; i2 < 16; ++i2)
          __hip_atomic_store(b + 32 + i2*32, 0u, __ATOMIC_RELAXED, __HIP_MEMORY_SCOPE_AGENT);
        __hip_atomic_store(b + 16, 0u, __ATOMIC_RELAXED, __HIP_MEMORY_SCOPE_AGENT);
        __hip_atomic_store(b, g + 1u, __ATOMIC_RELEASE, __HIP_MEMORY_SCOPE_AGENT);
        done = true;
      }
    }
    if (!done) {
      while (__hip_atomic_load(b, __ATOMIC_ACQUIRE, __HIP_MEMORY_SCOPE_AGENT) == g)
        __builtin_amdgcn_s_sleep(2);
    }
  }
  __syncthreads();
}

// stage W (70x70 row-major) -> slab transposed [72][80], pads zero.
__device__ __forceinline__ void stage_wt(float* __restrict__ slab,
                                         const float* __restrict__ W, int tid) {
  for (int i = tid; i < 72*SLS; i += TPB) {
    int j = i / SLS, K = i % SLS;
    slab[i] = (j < DD && K < DD) ? W[K*DD + j] : 0.f;
  }
}

__global__ void __launch_bounds__(TPB, 2) gps_kernel(GPSParams p) {
  extern __shared__ float smem[];
  float* eT    = smem + OFF_ET;
  float* hN    = smem + OFF_HN;
  float* Ax    = smem + OFF_AX;
  float* Bx    = smem + OFF_BX;
  float* Dx    = smem + OFF_DX;
  float* Ex    = smem + OFF_EX;
  float* slab  = smem + OFF_SLAB;
  float* statl = smem + OFF_STATL;
  int*   icur  = (int*)(smem + SMEM_FLOATS);
  int*   ioff  = icur + 32;
  unsigned char* srcloc = (unsigned char*)(ioff + 33);
  unsigned char* dstloc = srcloc + 256;
  unsigned char* eidxL  = dstloc + 256;

  const int tid  = threadIdx.x;
  const int g    = blockIdx.x;
  const int lane = tid & 63;

  // edge roles
  const int rb  = tid & 63;        // 4-edge block
  const int cge = tid >> 6;        // col group (== wave)
  const int jbe = cge * 9;
  const int e0  = 4 * rb;

  float* slot = p.stats + (((g >> 5) * NLAYERS)) * SPL;  // + L*SPL later

  // ---------------- CSR build ----------------
  if (tid < 32) icur[tid] = 0;
  __syncthreads();
  if (tid < 256) {
    int s0 = p.ei[g*256 + tid]         - g*32;
    int d0 = p.ei[65536 + g*256 + tid] - g*32;
    srcloc[tid] = (unsigned char)s0;
    dstloc[tid] = (unsigned char)d0;
    atomicAdd(&icur[d0], 1);
  }
  __syncthreads();
  if (tid == 0) {
    int o = 0;
    for (int n = 0; n < 32; ++n) { ioff[n] = o; o += icur[n]; }
    ioff[32] = o;
  }
  __syncthreads();
  if (tid < 32) icur[tid] = ioff[tid];
  __syncthreads();
  if (tid < 256) {
    int d0 = dstloc[tid];
    int sl2 = atomicAdd(&icur[d0], 1);
    eidxL[sl2] = (unsigned char)tid;
  }

  // ---------------- init ----------------
  for (int i = tid; i < 5*32*NBS; i += TPB) hN[i] = 0.f;   // hN..Ex contiguous
  for (int i = tid; i < STATL_F; i += TPB) statl[i] = 0.f;
  __syncthreads();
  for (int i = tid; i < 32*DD; i += TPB) {
    int n = i / DD, j = i % DD;
    hN[n*NBS + j] = fmaf(p.x[g*32 + n], p.wn[j], p.bnn[j]);
  }
  for (int i = tid; i < DD*ETS; i += TPB) {
    int k = i >> 8, e = i & 255;
    eT[i] = fmaf(p.ea[g*256 + e], p.we[k], p.web[k]);
  }
  __syncthreads();

  // node-gemm roles
  const int n_cg = tid >> 6;          // col group
  const int n_jb = n_cg * 9;
  const int n_kh = (tid >> 5) & 1;    // k-half (lane bit 5)
  const int n_n  = tid & 31;          // node
  const int n_kb = n_kh * 40;

  auto node_phase = [&](const float* __restrict__ W, float* __restrict__ nbuf, int boff) {
    stage_wt(slab, W, tid);
    __syncthreads();
    float acc[9];
    #pragma unroll
    for (int i = 0; i < 9; ++i) acc[i] = 0.f;
    const float* hrow = hN + n_n*NBS;
    #pragma unroll 1
    for (int c = 0; c < 5; ++c) {
      const int K0 = n_kb + c*8;
      float4 h03 = *(const float4*)(hrow + K0);
      float4 h47 = *(const float4*)(hrow + K0 + 4);
      #pragma unroll
      for (int i = 0; i < 9; ++i) {
        const float* wr = slab + (n_jb + i)*SLS + K0;
        float4 w03 = *(const float4*)(wr);
        float4 w47 = *(const float4*)(wr + 4);
        acc[i] = fmaf(h03.x, w03.x, acc[i]); acc[i] = fmaf(h03.y, w03.y, acc[i]);
        acc[i] = fmaf(h03.z, w03.z, acc[i]); acc[i] = fmaf(h03.w, w03.w, acc[i]);
        acc[i] = fmaf(h47.x, w47.x, acc[i]); acc[i] = fmaf(h47.y, w47.y, acc[i]);
        acc[i] = fmaf(h47.z, w47.z, acc[i]); acc[i] = fmaf(h47.w, w47.w, acc[i]);
      }
    }
    #pragma unroll
    for (int i = 0; i < 9; ++i) acc[i] += __shfl_xor(acc[i], 32, 64);
    if (n_kh == 0) {
      #pragma unroll
      for (int i = 0; i < 9; ++i) {
        int j = n_jb + i;
        if (j < DD) nbuf[n_n*NBS + j] = acc[i] + statl[boff + j];
      }
    }
    __syncthreads();
  };

  // ---------------- layer loop ----------------
  #pragma unroll 1
  for (int L = 0; L < NLAYERS; ++L) {
    const int s = (L == 0) ? 0 : 1;
    float* lslot = slot + L * SPL;

    if (tid < DD) {
      statl[BAO + tid] = p.Ab[s][tid];
      statl[BBO + tid] = p.Bb[s][tid];
      statl[SBO + tid] = p.Cb[s][tid] + p.Db[s][tid] + p.Eb[s][tid];
    }
    node_phase(p.Aw[s], Ax, BAO);
    node_phase(p.Bw[s], Bx, BBO);
    node_phase(p.Dw[s], Dx, ZBO);
    node_phase(p.Ew[s], Ex, ZBO);

    stage_wt(slab, p.Cw[s], tid);
    __syncthreads();

    // ---- edge GEMM: acc[r][i] = sum_k e[e0+r][k] * Cw[k][jbe+i]
    float acc[4][9];
    #pragma unroll
    for (int r = 0; r < 4; ++r)
      #pragma unroll
      for (int i = 0; i < 9; ++i) acc[r][i] = 0.f;

#define FMA4(EV, WK, I) \
    acc[0][I] = fmaf((EV).x, (WK), acc[0][I]); \
    acc[1][I] = fmaf((EV).y, (WK), acc[1][I]); \
    acc[2][I] = fmaf((EV).z, (WK), acc[2][I]); \
    acc[3][I] = fmaf((EV).w, (WK), acc[3][I]);

    #pragma unroll 1
    for (int c = 0; c < 8; ++c) {
      const int K0 = c*8;
      float4 ev[8];
      #pragma unroll
      for (int kk = 0; kk < 8; ++kk)
        ev[kk] = *(const float4*)(eT + (K0 + kk)*ETS + e0);
      #pragma unroll
      for (int i = 0; i < 9; ++i) {
        const float* wr = slab + (jbe + i)*SLS + K0;
        float4 w03 = *(const float4*)(wr);
        float4 w47 = *(const float4*)(wr + 4);
        FMA4(ev[0], w03.x, i) FMA4(ev[1], w03.y, i) FMA4(ev[2], w03.z, i) FMA4(ev[3], w03.w, i)
        FMA4(ev[4], w47.x, i) FMA4(ev[5], w47.y, i) FMA4(ev[6], w47.z, i) FMA4(ev[7], w47.w, i)
      }
    }
    { // tail k = 64..69
      float4 ev[6];
      #pragma unroll
      for (int kk = 0; kk < 6; ++kk)
        ev[kk] = *(const float4*)(eT + (64 + kk)*ETS + e0);
      #pragma unroll
      for (int i = 0; i < 9; ++i) {
        const float* wr = slab + (jbe + i)*SLS + 64;
        float4 w03 = *(const float4*)(wr);
        float2 w45 = *(const float2*)(wr + 4);
        FMA4(ev[0], w03.x, i) FMA4(ev[1], w03.y, i) FMA4(ev[2], w03.z, i) FMA4(ev[3], w03.w, i)
        FMA4(ev[4], w45.x, i) FMA4(ev[5], w45.y, i)
      }
    }

    // eold (residual base), then += Dx[dst] + Ex[src] + (Cb+Db+Eb)
    float4 eo[9];
    #pragma unroll
    for (int i = 0; i < 9; ++i) {
      int j = jbe + i;
      if (j < DD) eo[i] = *(const float4*)(eT + j*ETS + e0);
      else { eo[i].x = eo[i].y = eo[i].z = eo[i].w = 0.f; }
    }
    #pragma unroll
    for (int r = 0; r < 4; ++r) {
      int dl = dstloc[e0 + r], sl2 = srcloc[e0 + r];
      const float* dxr = Dx + dl*NBS;
      const float* exr = Ex + sl2*NBS;
      #pragma unroll
      for (int i = 0; i < 9; ++i) {
        int j = jbe + i;
        if (j < DD) acc[r][i] += dxr[j] + exr[j] + statl[SBO + j];
      }
    }

    // e-stats from registers: wave shfl reduction (all lanes same cge)
    #pragma unroll
    for (int i = 0; i < 9; ++i) {
      float ps = acc[0][i] + acc[1][i] + acc[2][i] + acc[3][i];
      float qs = acc[0][i]*acc[0][i];
      qs = fmaf(acc[1][i], acc[1][i], qs);
      qs = fmaf(acc[2][i], acc[2][i], qs);
      qs = fmaf(acc[3][i], acc[3][i], qs);
      #pragma unroll
      for (int d = 1; d < 64; d <<= 1) {
        ps += __shfl_xor(ps, d, 64);
        qs += __shfl_xor(qs, d, 64);
      }
      if (lane == 0) {
        int j = jbe + i;
        if (j < DD) {
          atomicAdd(lslot + 140 + j, ps);
          atomicAdd(lslot + 210 + j, qs);
        }
      }
    }
    __syncthreads();   // all eT reads (gemm + eold) complete

    // sigmoid in place into eT
    #pragma unroll
    for (int i = 0; i < 9; ++i) {
      int j = jbe + i;
      if (j < DD) {
        float4 sg;
        sg.x = 1.f / (1.f + __expf(-acc[0][i]));
        sg.y = 1.f / (1.f + __expf(-acc[1][i]));
        sg.z = 1.f / (1.f + __expf(-acc[2][i]));
        sg.w = 1.f / (1.f + __expf(-acc[3][i]));
        *(float4*)(eT + j*ETS + e0) = sg;
      }
    }
    __syncthreads();

    // gather: x_new = Ax + num/den (into Ax)
    {
      auto gath = [&](int item) {
        int n = item / 18, jq = item % 18;
        int j0 = jq * 4;
        bool v2 = (j0 + 2) < DD, v3 = (j0 + 3) < DD;
        float nm0 = 0.f, nm1 = 0.f, nm2 = 0.f, nm3 = 0.f;
        float dn0 = 0.f, dn1 = 0.f, dn2 = 0.f, dn3 = 0.f;
        int pb = ioff[n], pe = ioff[n + 1];
        for (int pp = pb; pp < pe; ++pp) {
          int e2 = eidxL[pp];
          int sl2 = srcloc[e2];
          float s0 = eT[(j0 + 0)*ETS + e2];
          float s1 = eT[(j0 + 1)*ETS + e2];
          float s2 = v2 ? eT[(j0 + 2)*ETS + e2] : 0.f;
          float s3 = v3 ? eT[(j0 + 3)*ETS + e2] : 0.f;
          float4 b4 = *(const float4*)(Bx + sl2*NBS + j0);
          nm0 = fmaf(s0, b4.x, nm0); nm1 = fmaf(s1, b4.y, nm1);
          nm2 = fmaf(s2, b4.z, nm2); nm3 = fmaf(s3, b4.w, nm3);
          dn0 += s0; dn1 += s1; dn2 += s2; dn3 += s3;
        }
        float* axp = Ax + n*NBS + j0;
        float4 ax = *(const float4*)axp;
        ax.x += nm0 / (dn0 + EPS_AGG);
        ax.y += nm1 / (dn1 + EPS_AGG);
        ax.z += nm2 / (dn2 + EPS_AGG);
        ax.w += nm3 / (dn3 + EPS_AGG);
        *(float4*)axp = ax;
      };
      gath(tid);
      if (tid < 64) gath(tid + 512);
    }
    __syncthreads();

    // x-stats
    if (tid < 140) {
      int col = tid % DD, hh = tid / DD;
      float sm = 0.f, sq = 0.f;
      #pragma unroll 4
      for (int r = 0; r < 16; ++r) {
        int rr = (r + col) & 15;
        float v = Ax[(hh*16 + rr)*NBS + col];
        sm += v; sq = fmaf(v, v, sq);
      }
      atomicAdd(lslot + col, sm);
      atomicAdd(lslot + 70 + col, sq);
    }

    grid_sync(p.bar);

    // BN scale/shift from 8 slots
    if (tid < DD) {
      float sm = 0.f, sq = 0.f;
      #pragma unroll
      for (int sl2 = 0; sl2 < NSLOT; ++sl2) {
        const float* st = p.stats + (sl2*NLAYERS + L)*SPL;
        sm += __hip_atomic_load(st + tid,      __ATOMIC_RELAXED, __HIP_MEMORY_SCOPE_AGENT);
        sq += __hip_atomic_load(st + 70 + tid, __ATOMIC_RELAXED, __HIP_MEMORY_SCOPE_AGENT);
      }
      float mean = sm * (1.f/8192.f);
      float var  = sq * (1.f/8192.f) - mean*mean;
      float sc = p.gx[s][tid] * rsqrtf(var + EPS_BN);
      statl[SCX + tid] = sc;
      statl[SHX + tid] = fmaf(-mean, sc, p.bx[s][tid]);
    } else if (tid < 140) {
      int j = tid - DD;
      float sm = 0.f, sq = 0.f;
      #pragma unroll
      for (int sl2 = 0; sl2 < NSLOT; ++sl2) {
        const float* st = p.stats + (sl2*NLAYERS + L)*SPL;
        sm += __hip_atomic_load(st + 140 + j, __ATOMIC_RELAXED, __HIP_MEMORY_SCOPE_AGENT);
        sq += __hip_atomic_load(st + 210 + j, __ATOMIC_RELAXED, __HIP_MEMORY_SCOPE_AGENT);
      }
      float mean = sm * (1.f/65536.f);
      float var  = sq * (1.f/65536.f) - mean*mean;
      float sc = p.ge[s][j] * rsqrtf(var + EPS_BN);
      statl[SCE + j] = sc;
      statl[SHE + j] = fmaf(-mean, sc, p.gbe[s][j]);
    }
    __syncthreads();

    // apply BN+ReLU+residual: h
    for (int i = tid; i < 32*DD; i += TPB) {
      int n = i / DD, j = i % DD;
      float xn = Ax[n*NBS + j];
      hN[n*NBS + j] += fmaxf(fmaf(xn, statl[SCX + j], statl[SHX + j]), 0.f);
    }
    // apply BN+ReLU+residual: e (from registers, write eT)
    #pragma unroll
    for (int i = 0; i < 9; ++i) {
      int j = jbe + i;
      if (j < DD) {
        float sc = statl[SCE + j], sh = statl[SHE + j];
        float4 r;
        r.x = eo[i].x + fmaxf(fmaf(acc[0][i], sc, sh), 0.f);
        r.y = eo[i].y + fmaxf(fmaf(acc[1][i], sc, sh), 0.f);
        r.z = eo[i].z + fmaxf(fmaf(acc[2][i], sc, sh), 0.f);
        r.w = eo[i].w + fmaxf(fmaf(acc[3][i], sc, sh), 0.f);
        *(float4*)(eT + j*ETS + e0) = r;
      }
    }
    __syncthreads();
  }

  // ---------------- readout ----------------
  if (tid < DD) {
    float mx = -3.4e38f, sm = 0.f;
    #pragma unroll 4
    for (int r = 0; r < 32; ++r) {
      float v = hN[r*NBS + tid];
      mx = fmaxf(mx, v); sm += v;
    }
    statl[tid]      = mx;               // gmp
    statl[72 + tid] = sm * (1.f/32.f);  // gap
  }
  __syncthreads();
  if (tid < 256) {
    float a = p.c1b[tid];
    for (int k = 0; k < DD; ++k) a = fmaf(statl[k],      p.c1w[k*256 + tid], a);
    for (int k = 0; k < DD; ++k) a = fmaf(statl[72 + k], p.c1w[(DD + k)*256 + tid], a);
    Ax[tid] = fmaxf(a, 0.f);
  }
  __syncthreads();
  if (tid == 0) {
    float sm = 0.f, sq = 0.f;
    for (int k = 0; k < 256; ++k) { float v = Ax[k]; sm += v; sq = fmaf(v, v, sq); }
    float mean = sm * (1.f/256.f);
    float var  = sq * (1.f/256.f) - mean*mean;
    statl[560] = mean;
    statl[561] = rsqrtf(var + EPS_LN);
  }
  __syncthreads();
  if (tid < 256) {
    float v = (Ax[tid] - statl[560]) * statl[561];
    Bx[tid] = fmaf(v, p.lng[tid], p.lnb[tid]);
  }
  __syncthreads();
  if (tid < 10) {
    float a = p.c2b[tid];
    for (int k = 0; k < 256; ++k) a = fmaf(Bx[k], p.c2w[k*10 + tid], a);
    p.out[g*10 + tid] = a;
  }
}

extern "C" void kernel_launch(void* const* d_in, const int* in_sizes, int n_in,
                              void* d_out, int out_size, void* d_ws, size_t ws_size,
                              hipStream_t stream) {
  (void)in_sizes; (void)n_in; (void)out_size; (void)ws_size;
  GPSParams p;
  p.x   = (const float*)d_in[0];
  p.ei  = (const int*)  d_in[1];
  p.ea  = (const float*)d_in[2];
  p.wn  = (const float*)d_in[4];  p.bnn = (const float*)d_in[5];
  p.we  = (const float*)d_in[6];  p.web = (const float*)d_in[7];
  int i = 8;
  for (int s = 0; s < 2; ++s) {
    p.Aw[s] = (const float*)d_in[i++]; p.Ab[s] = (const float*)d_in[i++];
    p.Bw[s] = (const float*)d_in[i++]; p.Bb[s] = (const float*)d_in[i++];
    p.Cw[s] = (const float*)d_in[i++]; p.Cb[s] = (const float*)d_in[i++];
    p.Dw[s] = (const float*)d_in[i++]; p.Db[s] = (const float*)d_in[i++];
    p.Ew[s] = (const float*)d_in[i++]; p.Eb[s] = (const float*)d_in[i++];
    p.gx[s] = (const float*)d_in[i++]; p.bx[s] = (const float*)d_in[i++];
    p.ge[s] = (const float*)d_in[i++]; p.gbe[s] = (const float*)d_in[i++];
  }
  p.c1w = (const float*)d_in[36]; p.c1b = (const float*)d_in[37];
  p.lng = (const float*)d_in[38]; p.lnb = (const float*)d_in[39];
  p.c2w = (const float*)d_in[40]; p.c2b = (const float*)d_in[41];
  p.out = (float*)d_out;
  p.bar = (unsigned*)d_ws;
  p.stats = (float*)((char*)d_ws + 4096);

  hipMemsetAsync(d_ws, 0, 4096 + NSLOT*NLAYERS*SPL*4, stream);

  hipFuncSetAttribute((const void*)gps_kernel,
                      hipFuncAttributeMaxDynamicSharedMemorySize, SMEM_BYTES);

  void* args[] = { (void*)&p };
  hipError_t err = hipLaunchCooperativeKernel((const void*)gps_kernel,
                                              dim3(NBLK), dim3(TPB),
                                              args, SMEM_BYTES, stream);
  if (err != hipSuccess) {
    gps_kernel<<<dim3(NBLK), dim3(TPB), SMEM_BYTES, stream>>>(p);
  }
}